// Round 1
// baseline (1075.496 us; speedup 1.0000x reference)
//
#include <hip/hip_runtime.h>
#include <hip/hip_bf16.h>

#define T_TOK 32768
#define D_DIM 128
#define E_EXP 32
#define K_TOP 8
#define DFF_DIM 512
#define TILE 64

// ---------------- Router: logits -> top8 -> softmax -> per-expert lists ----------------
extern "C" __global__ __launch_bounds__(256)
void moe_router(const float* __restrict__ x, const float* __restrict__ Wr,
                const float* __restrict__ br, int* __restrict__ g_cnt,
                int* __restrict__ list_tok, float* __restrict__ list_gate)
{
    __shared__ float Wrs[E_EXP * D_DIM];
    __shared__ float brs[E_EXP];
    __shared__ int cnt_s[E_EXP];
    __shared__ int base_s[E_EXP];
    const int tid = threadIdx.x;
    for (int i = tid; i < E_EXP * D_DIM; i += 256) Wrs[i] = Wr[i];
    if (tid < E_EXP) { brs[tid] = br[tid]; cnt_s[tid] = 0; }
    __syncthreads();

    const int t = blockIdx.x * 256 + tid;
    float logits[E_EXP];
    #pragma unroll
    for (int e = 0; e < E_EXP; ++e) logits[e] = brs[e];

    const float4* xr = reinterpret_cast<const float4*>(x + (size_t)t * D_DIM);
    for (int dc = 0; dc < D_DIM / 4; ++dc) {
        const float4 xv = xr[dc];
        #pragma unroll
        for (int e = 0; e < E_EXP; ++e) {
            const float4 wv = reinterpret_cast<const float4*>(Wrs + e * D_DIM)[dc];
            logits[e] = fmaf(xv.x, wv.x, fmaf(xv.y, wv.y, fmaf(xv.z, wv.z, fmaf(xv.w, wv.w, logits[e]))));
        }
    }

    // top-8, strict '>' => lowest index wins ties (matches lax.top_k)
    float vals[K_TOP]; int ids[K_TOP];
    #pragma unroll
    for (int k = 0; k < K_TOP; ++k) {
        float m = -3e38f; int mi = 0;
        #pragma unroll
        for (int e = 0; e < E_EXP; ++e) {
            if (logits[e] > m) { m = logits[e]; mi = e; }
        }
        vals[k] = m; ids[k] = mi;
        #pragma unroll
        for (int e = 0; e < E_EXP; ++e) if (e == mi) logits[e] = -3e38f;  // static idx only
    }
    float s = 0.f, w[K_TOP];
    #pragma unroll
    for (int k = 0; k < K_TOP; ++k) { w[k] = expf(vals[k] - vals[0]); s += w[k]; }
    const float inv = 1.f / s;

    // block-local aggregation, then one global atomic per expert per block
    int pos[K_TOP];
    #pragma unroll
    for (int k = 0; k < K_TOP; ++k) pos[k] = atomicAdd(&cnt_s[ids[k]], 1);
    __syncthreads();
    if (tid < E_EXP) base_s[tid] = atomicAdd(&g_cnt[tid], cnt_s[tid]);
    __syncthreads();
    #pragma unroll
    for (int k = 0; k < K_TOP; ++k) {
        const int e = ids[k];
        const int p = base_s[e] + pos[k];
        list_tok[e * T_TOK + p]  = t;
        list_gate[e * T_TOK + p] = w[k] * inv;
    }
}

// ---------------- Expert FFN: gathered 64-token tile, fused two GEMMs ----------------
extern "C" __global__ __launch_bounds__(256)
void moe_ffn(const float* __restrict__ x, const float* __restrict__ W1,
             const float* __restrict__ b1, const float* __restrict__ W2,
             const float* __restrict__ b2, const int* __restrict__ g_cnt,
             const int* __restrict__ list_tok, const float* __restrict__ list_gate,
             float* __restrict__ out)
{
    const int e = blockIdx.y;
    const int cnt = g_cnt[e];
    const int tile0 = blockIdx.x * TILE;
    if (tile0 >= cnt) return;

    __shared__ float Xs[D_DIM * TILE];   // [d][t], 32 KB
    __shared__ float Ws[128 * 64];       // union: W1 chunk [d][f] / W2 chunk [f][d], 32 KB
    __shared__ float Hs[TILE * 64];      // [t][f], 16 KB   (total 80 KB -> 2 blocks/CU)
    const int tid = threadIdx.x;

    // ---- gather X tile, transposed into Xs[d][t] ----
    {
        const int tt = tid & 63;
        const int dg = tid >> 6;           // 0..3
        const int gt = tile0 + tt;
        const bool v = gt < cnt;
        int tok = 0;
        if (v) tok = list_tok[e * T_TOK + gt];
        const float4* xr = reinterpret_cast<const float4*>(x + (size_t)tok * D_DIM);
        #pragma unroll
        for (int c = 0; c < 8; ++c) {
            const int d4 = dg * 8 + c;     // 0..31
            const float4 xv = v ? xr[d4] : make_float4(0.f, 0.f, 0.f, 0.f);
            Xs[(d4 * 4 + 0) * TILE + tt] = xv.x;
            Xs[(d4 * 4 + 1) * TILE + tt] = xv.y;
            Xs[(d4 * 4 + 2) * TILE + tt] = xv.z;
            Xs[(d4 * 4 + 3) * TILE + tt] = xv.w;
        }
    }

    // out-phase mapping: 8 tokens x 4 dims per thread
    const int d0  = (tid & 31) * 4;
    const int t0o = (tid >> 5) * 8;
    float acc[8][4];
    #pragma unroll
    for (int i = 0; i < 8; ++i)
        #pragma unroll
        for (int j = 0; j < 4; ++j) acc[i][j] = 0.f;

    // H-phase mapping: 4 tokens x 4 dff per thread
    const int f0  = (tid & 15) * 4;
    const int t0h = (tid >> 4) * 4;

    for (int c = 0; c < DFF_DIM / 64; ++c) {
        __syncthreads();  // previous phase readers done with Ws / Xs
        // stage W1 chunk [128 d][64 f]
        {
            const float* W1e = W1 + (size_t)e * D_DIM * DFF_DIM + c * 64;
            #pragma unroll
            for (int r = 0; r < 8; ++r) {
                const int i  = r * 256 + tid;    // 0..2047 float4 slots
                const int d  = i >> 4;
                const int c4 = i & 15;
                const float4 v = reinterpret_cast<const float4*>(W1e + (size_t)d * DFF_DIM)[c4];
                reinterpret_cast<float4*>(Ws + d * 64)[c4] = v;
            }
        }
        __syncthreads();
        // H = relu(X W1 + b1)
        {
            float h[4][4];
            const float4 bv = reinterpret_cast<const float4*>(b1 + (size_t)e * DFF_DIM + c * 64)[f0 >> 2];
            #pragma unroll
            for (int i = 0; i < 4; ++i) { h[i][0] = bv.x; h[i][1] = bv.y; h[i][2] = bv.z; h[i][3] = bv.w; }
            #pragma unroll 4
            for (int d = 0; d < D_DIM; ++d) {
                const float4 xv = *reinterpret_cast<const float4*>(Xs + d * TILE + t0h);
                const float4 wv = *reinterpret_cast<const float4*>(Ws + d * 64 + f0);
                const float tx[4] = {xv.x, xv.y, xv.z, xv.w};
                const float tw[4] = {wv.x, wv.y, wv.z, wv.w};
                #pragma unroll
                for (int i = 0; i < 4; ++i)
                    #pragma unroll
                    for (int j = 0; j < 4; ++j)
                        h[i][j] = fmaf(tx[i], tw[j], h[i][j]);
            }
            #pragma unroll
            for (int i = 0; i < 4; ++i) {
                float4 hv;
                hv.x = fmaxf(h[i][0], 0.f);
                hv.y = fmaxf(h[i][1], 0.f);
                hv.z = fmaxf(h[i][2], 0.f);
                hv.w = fmaxf(h[i][3], 0.f);
                *reinterpret_cast<float4*>(Hs + (t0h + i) * 64 + f0) = hv;
            }
        }
        __syncthreads();
        // stage W2 chunk [64 f][128 d] (contiguous block)
        {
            const float* W2e = W2 + (size_t)e * DFF_DIM * D_DIM + (size_t)(c * 64) * D_DIM;
            #pragma unroll
            for (int r = 0; r < 8; ++r) {
                const int i = r * 256 + tid;     // 0..2047 float4 slots
                reinterpret_cast<float4*>(Ws)[i] = reinterpret_cast<const float4*>(W2e)[i];
            }
        }
        __syncthreads();
        // acc += relu(H) @ W2
        {
            #pragma unroll 2
            for (int fb = 0; fb < 16; ++fb) {
                const int f = fb * 4;
                float tw[4][4];
                #pragma unroll
                for (int k = 0; k < 4; ++k) {
                    const float4 wv = *reinterpret_cast<const float4*>(Ws + (f + k) * 128 + d0);
                    tw[k][0] = wv.x; tw[k][1] = wv.y; tw[k][2] = wv.z; tw[k][3] = wv.w;
                }
                #pragma unroll
                for (int i = 0; i < 8; ++i) {
                    const float4 hv = *reinterpret_cast<const float4*>(Hs + (t0o + i) * 64 + f);
                    const float th[4] = {hv.x, hv.y, hv.z, hv.w};
                    #pragma unroll
                    for (int k = 0; k < 4; ++k)
                        #pragma unroll
                        for (int j = 0; j < 4; ++j)
                            acc[i][j] = fmaf(th[k], tw[k][j], acc[i][j]);
                }
            }
        }
    }

    // epilogue: out[tok] += gate * (acc + b2)
    const float4 b2v = reinterpret_cast<const float4*>(b2 + (size_t)e * D_DIM)[d0 >> 2];
    #pragma unroll
    for (int i = 0; i < 8; ++i) {
        const int gt = tile0 + t0o + i;
        if (gt < cnt) {
            const int   tok = list_tok[e * T_TOK + gt];
            const float g   = list_gate[e * T_TOK + gt];
            float* orow = out + (size_t)tok * D_DIM + d0;
            atomicAdd(orow + 0, g * (acc[i][0] + b2v.x));
            atomicAdd(orow + 1, g * (acc[i][1] + b2v.y));
            atomicAdd(orow + 2, g * (acc[i][2] + b2v.z));
            atomicAdd(orow + 3, g * (acc[i][3] + b2v.w));
        }
    }
}

extern "C" void kernel_launch(void* const* d_in, const int* in_sizes, int n_in,
                              void* d_out, int out_size, void* d_ws, size_t ws_size,
                              hipStream_t stream)
{
    const float* x  = (const float*)d_in[0];
    const float* Wr = (const float*)d_in[1];
    const float* br = (const float*)d_in[2];
    const float* W1 = (const float*)d_in[3];
    const float* b1 = (const float*)d_in[4];
    const float* W2 = (const float*)d_in[5];
    const float* b2 = (const float*)d_in[6];
    float* out = (float*)d_out;

    char* ws = (char*)d_ws;
    int*   g_cnt     = (int*)ws;                                        // 128 B
    int*   list_tok  = (int*)(ws + 256);                                // 4 MB
    float* list_gate = (float*)(ws + 256 + (size_t)E_EXP * T_TOK * 4);  // 4 MB

    hipMemsetAsync(g_cnt, 0, E_EXP * sizeof(int), stream);
    hipMemsetAsync(out, 0, (size_t)out_size * sizeof(float), stream);

    moe_router<<<dim3(T_TOK / 256), dim3(256), 0, stream>>>(x, Wr, br, g_cnt, list_tok, list_gate);
    moe_ffn<<<dim3(T_TOK / TILE, E_EXP), dim3(256), 0, stream>>>(x, W1, b1, W2, b2, g_cnt,
                                                                 list_tok, list_gate, out);
}

// Round 3
// 598.568 us; speedup vs baseline: 1.7968x; 1.7968x over previous
//
#include <hip/hip_runtime.h>
#include <hip/hip_bf16.h>
#include <stdint.h>

#define T_TOK 32768
#define D_DIM 128
#define E_EXP 32
#define K_TOP 8
#define DFF_DIM 512
#define TILE 128          // tokens per ffn block
#define NCHUNK 8          // DFF chunks of 64

typedef __attribute__((ext_vector_type(8))) short  s16x8;
typedef __attribute__((ext_vector_type(4))) float  f32x4;

__device__ inline unsigned short f2bf(float f) {
    union { float f; unsigned u; } v; v.f = f;
    unsigned r = (v.u + 0x7fffu + ((v.u >> 16) & 1u)) >> 16;
    return (unsigned short)r;
}

// ---------------- convert: x -> bf16, W1/W2 -> fragment-linear bf16 ----------------
// W1t frag id = (((e*8 + fc)*4 + s)*4 + n)*64 + l ; elem j: W1[e][d=32s+8*(l>>4)+j][f=64fc+16n+(l&15)]
// W2t frag id = (((e*8 + fc)*2 + sp)*8 + n)*64 + l; elem j: W2[e][f=64fc+32sp+8*(l>>4)+j][dout=16n+(l&15)]
extern "C" __global__ __launch_bounds__(256)
void moe_convert(const float* __restrict__ x, const float* __restrict__ W1,
                 const float* __restrict__ W2, unsigned short* __restrict__ xb,
                 unsigned short* __restrict__ W1t, unsigned short* __restrict__ W2t)
{
    const int b = blockIdx.x, t = threadIdx.x;
    if (b < 2048) {
        const size_t i0 = ((size_t)b * 256 + t) * 8;
        const float4 a = *reinterpret_cast<const float4*>(x + i0);
        const float4 c = *reinterpret_cast<const float4*>(x + i0 + 4);
        s16x8 v;
        v[0]=(short)f2bf(a.x); v[1]=(short)f2bf(a.y); v[2]=(short)f2bf(a.z); v[3]=(short)f2bf(a.w);
        v[4]=(short)f2bf(c.x); v[5]=(short)f2bf(c.y); v[6]=(short)f2bf(c.z); v[7]=(short)f2bf(c.w);
        *reinterpret_cast<s16x8*>(xb + i0) = v;
    } else if (b < 3072) {
        const int fid = (b - 2048) * 256 + t;     // 0..262143
        const int l  = fid & 63;
        const int n  = (fid >> 6) & 3;
        const int s  = (fid >> 8) & 3;
        const int fc = (fid >> 10) & 7;
        const int e  = fid >> 13;
        const int f  = fc * 64 + n * 16 + (l & 15);
        const int d0 = s * 32 + (l >> 4) * 8;
        s16x8 v;
        #pragma unroll
        for (int j = 0; j < 8; ++j)
            v[j] = (short)f2bf(W1[((size_t)e * D_DIM + d0 + j) * DFF_DIM + f]);
        *reinterpret_cast<s16x8*>(W1t + (size_t)fid * 8) = v;
    } else {
        const int fid = (b - 3072) * 256 + t;
        const int l  = fid & 63;
        const int n  = (fid >> 6) & 7;
        const int sp = (fid >> 9) & 1;
        const int fc = (fid >> 10) & 7;
        const int e  = fid >> 13;
        const int dout = n * 16 + (l & 15);
        const int f0   = fc * 64 + sp * 32 + (l >> 4) * 8;
        s16x8 v;
        #pragma unroll
        for (int j = 0; j < 8; ++j)
            v[j] = (short)f2bf(W2[((size_t)e * DFF_DIM + f0 + j) * D_DIM + dout]);
        *reinterpret_cast<s16x8*>(W2t + (size_t)fid * 8) = v;
    }
}

// ---------------- Router (unchanged from R1, known-good) ----------------
extern "C" __global__ __launch_bounds__(256)
void moe_router(const float* __restrict__ x, const float* __restrict__ Wr,
                const float* __restrict__ br, int* __restrict__ g_cnt,
                int* __restrict__ list_tok, float* __restrict__ list_gate)
{
    __shared__ float Wrs[E_EXP * D_DIM];
    __shared__ float brs[E_EXP];
    __shared__ int cnt_s[E_EXP];
    __shared__ int base_s[E_EXP];
    const int tid = threadIdx.x;
    for (int i = tid; i < E_EXP * D_DIM; i += 256) Wrs[i] = Wr[i];
    if (tid < E_EXP) { brs[tid] = br[tid]; cnt_s[tid] = 0; }
    __syncthreads();

    const int t = blockIdx.x * 256 + tid;
    float logits[E_EXP];
    #pragma unroll
    for (int e = 0; e < E_EXP; ++e) logits[e] = brs[e];

    const float4* xr = reinterpret_cast<const float4*>(x + (size_t)t * D_DIM);
    for (int dc = 0; dc < D_DIM / 4; ++dc) {
        const float4 xv = xr[dc];
        #pragma unroll
        for (int e = 0; e < E_EXP; ++e) {
            const float4 wv = reinterpret_cast<const float4*>(Wrs + e * D_DIM)[dc];
            logits[e] = fmaf(xv.x, wv.x, fmaf(xv.y, wv.y, fmaf(xv.z, wv.z, fmaf(xv.w, wv.w, logits[e]))));
        }
    }

    float vals[K_TOP]; int ids[K_TOP];
    #pragma unroll
    for (int k = 0; k < K_TOP; ++k) {
        float m = -3e38f; int mi = 0;
        #pragma unroll
        for (int e = 0; e < E_EXP; ++e) if (logits[e] > m) { m = logits[e]; mi = e; }
        vals[k] = m; ids[k] = mi;
        #pragma unroll
        for (int e = 0; e < E_EXP; ++e) if (e == mi) logits[e] = -3e38f;
    }
    float s = 0.f, w[K_TOP];
    #pragma unroll
    for (int k = 0; k < K_TOP; ++k) { w[k] = expf(vals[k] - vals[0]); s += w[k]; }
    const float inv = 1.f / s;

    int pos[K_TOP];
    #pragma unroll
    for (int k = 0; k < K_TOP; ++k) pos[k] = atomicAdd(&cnt_s[ids[k]], 1);
    __syncthreads();
    if (tid < E_EXP) base_s[tid] = atomicAdd(&g_cnt[tid], cnt_s[tid]);
    __syncthreads();
    #pragma unroll
    for (int k = 0; k < K_TOP; ++k) {
        const int e = ids[k];
        const int p = base_s[e] + pos[k];
        list_tok[e * T_TOK + p]  = t;
        list_gate[e * T_TOK + p] = w[k] * inv;
    }
}

// ---------------- MFMA expert FFN ----------------
// GEMM1 (swapped): C1t[f][tok] = mfma(A=W1t frag, B=X frag)
// GEMM2 (swapped): C2t[dout][tok] = mfma(A=W2t frag, B=H frag)
extern "C" __global__ __launch_bounds__(256, 2)
void moe_ffn(const unsigned short* __restrict__ xb,
             const unsigned short* __restrict__ W1t,
             const unsigned short* __restrict__ W2t,
             const float* __restrict__ b1, const float* __restrict__ b2,
             const int* __restrict__ g_cnt, const int* __restrict__ list_tok,
             const float* __restrict__ list_gate, float* __restrict__ out)
{
    const int e = blockIdx.y;
    const int cnt = g_cnt[e];
    const int tile0 = blockIdx.x * TILE;
    if (tile0 >= cnt) return;

    __shared__ unsigned short Xs[TILE * D_DIM];   // 32 KB  fragment-linear: ((m*4+s)*64+l)*8 elems
    __shared__ unsigned short Ws[64 * D_DIM];     // 16 KB  union: W1 chunk / W2 chunk (fragment-linear)
    __shared__ unsigned short Hs[TILE * 64];      // 16 KB  [tok][f] row-major, 16B-slot XOR swizzled

    const int tid  = threadIdx.x;
    const int lane = tid & 63;
    const int w    = tid >> 6;
    const int lo   = lane & 15, hi = lane >> 4;

    // ---- gather X fragments (bf16) ----
    #pragma unroll
    for (int it = 0; it < 8; ++it) {
        const int fid = it * 256 + tid;
        const int l = fid & 63, s = (fid >> 6) & 3, m = fid >> 8;
        const int gt = tile0 + m * 16 + (l & 15);
        s16x8 v = {0,0,0,0,0,0,0,0};
        if (gt < cnt) {
            const int tok = list_tok[e * T_TOK + gt];
            v = *reinterpret_cast<const s16x8*>(xb + (size_t)tok * D_DIM + s * 32 + (l >> 4) * 8);
        }
        *reinterpret_cast<s16x8*>(Xs + fid * 8) = v;
    }

    f32x4 acc2[4][4];
    #pragma unroll
    for (int i = 0; i < 4; ++i)
        #pragma unroll
        for (int j = 0; j < 4; ++j) acc2[i][j] = (f32x4){0.f, 0.f, 0.f, 0.f};

    const int wm = w & 1, wn = w >> 1;   // GEMM1: wm = token half, wn = f pair
    const int wt = w & 1, wd = w >> 1;   // GEMM2: wt = token half, wd = dout half

    for (int fc = 0; fc < NCHUNK; ++fc) {
        __syncthreads();
        // stage W1 chunk (16 KB, linear)
        {
            const unsigned short* src = W1t + (size_t)(e * 8 + fc) * 8192;
            #pragma unroll
            for (int it = 0; it < 4; ++it) {
                const int i = it * 256 + tid;
                *reinterpret_cast<s16x8*>(Ws + i * 8) =
                    *reinterpret_cast<const s16x8*>(src + i * 8);
            }
        }
        __syncthreads();

        // ---- GEMM1: 32 MFMA/wave ----
        f32x4 acc1[4][2];
        #pragma unroll
        for (int m = 0; m < 4; ++m) { acc1[m][0] = (f32x4){0,0,0,0}; acc1[m][1] = (f32x4){0,0,0,0}; }
        #pragma unroll
        for (int s = 0; s < 4; ++s) {
            const s16x8 a0 = *reinterpret_cast<const s16x8*>(Ws + ((s * 4 + wn * 2 + 0) * 64 + lane) * 8);
            const s16x8 a1 = *reinterpret_cast<const s16x8*>(Ws + ((s * 4 + wn * 2 + 1) * 64 + lane) * 8);
            #pragma unroll
            for (int m = 0; m < 4; ++m) {
                const s16x8 bx = *reinterpret_cast<const s16x8*>(Xs + (((wm * 4 + m) * 4 + s) * 64 + lane) * 8);
                acc1[m][0] = __builtin_amdgcn_mfma_f32_16x16x32_bf16(a0, bx, acc1[m][0], 0, 0, 0);
                acc1[m][1] = __builtin_amdgcn_mfma_f32_16x16x32_bf16(a1, bx, acc1[m][1], 0, 0, 0);
            }
        }

        // bias + relu + pack to Hs[tok][f] (swizzled), 8 x ds_write_b64 per lane
        #pragma unroll
        for (int nn = 0; nn < 2; ++nn) {
            const f32x4 b1v = *reinterpret_cast<const f32x4*>(
                b1 + (size_t)e * DFF_DIM + fc * 64 + (wn * 2 + nn) * 16 + 4 * hi);
            #pragma unroll
            for (int m = 0; m < 4; ++m) {
                f32x4 v = acc1[m][nn];
                const float h0 = fmaxf(v[0] + b1v[0], 0.f);
                const float h1 = fmaxf(v[1] + b1v[1], 0.f);
                const float h2 = fmaxf(v[2] + b1v[2], 0.f);
                const float h3 = fmaxf(v[3] + b1v[3], 0.f);
                const unsigned w0 = (unsigned)f2bf(h0) | ((unsigned)f2bf(h1) << 16);
                const unsigned w1 = (unsigned)f2bf(h2) | ((unsigned)f2bf(h3) << 16);
                const int row  = (wm * 4 + m) * 16 + lo;          // token-in-tile
                const int slot = ((wn * 2 + nn) * 2 + (hi >> 1)) ^ (row & 7);
                char* p = reinterpret_cast<char*>(Hs) + row * 128 + slot * 16 + (hi & 1) * 8;
                *reinterpret_cast<uint2*>(p) = make_uint2(w0, w1);
            }
        }
        __syncthreads();

        // stage W2 chunk (16 KB, linear)
        {
            const unsigned short* src = W2t + (size_t)(e * 8 + fc) * 8192;
            #pragma unroll
            for (int it = 0; it < 4; ++it) {
                const int i = it * 256 + tid;
                *reinterpret_cast<s16x8*>(Ws + i * 8) =
                    *reinterpret_cast<const s16x8*>(src + i * 8);
            }
        }
        __syncthreads();

        // ---- GEMM2: 32 MFMA/wave, accumulate acc2 across chunks ----
        #pragma unroll
        for (int sp = 0; sp < 2; ++sp) {
            s16x8 bh[4];
            #pragma unroll
            for (int tn = 0; tn < 4; ++tn) {
                const int row  = (wt * 4 + tn) * 16 + lo;
                const int slot = (sp * 4 + hi) ^ (row & 7);
                bh[tn] = *reinterpret_cast<const s16x8*>(
                    reinterpret_cast<char*>(Hs) + row * 128 + slot * 16);
            }
            #pragma unroll
            for (int dn = 0; dn < 4; ++dn) {
                const s16x8 aw = *reinterpret_cast<const s16x8*>(
                    Ws + ((sp * 8 + wd * 4 + dn) * 64 + lane) * 8);
                acc2[dn][0] = __builtin_amdgcn_mfma_f32_16x16x32_bf16(aw, bh[0], acc2[dn][0], 0, 0, 0);
                acc2[dn][1] = __builtin_amdgcn_mfma_f32_16x16x32_bf16(aw, bh[1], acc2[dn][1], 0, 0, 0);
                acc2[dn][2] = __builtin_amdgcn_mfma_f32_16x16x32_bf16(aw, bh[2], acc2[dn][2], 0, 0, 0);
                acc2[dn][3] = __builtin_amdgcn_mfma_f32_16x16x32_bf16(aw, bh[3], acc2[dn][3], 0, 0, 0);
            }
        }
    }

    // ---- epilogue: out[tok][dout] += gate * (acc2 + b2) ----
    #pragma unroll
    for (int tn = 0; tn < 4; ++tn) {
        const int gt = tile0 + (wt * 4 + tn) * 16 + lo;
        int tok = -1; float g = 0.f;
        if (gt < cnt) { tok = list_tok[e * T_TOK + gt]; g = list_gate[e * T_TOK + gt]; }
        if (tok >= 0) {
            float* orow = out + (size_t)tok * D_DIM;
            #pragma unroll
            for (int dn = 0; dn < 4; ++dn) {
                const int dout = (wd * 4 + dn) * 16 + 4 * hi;
                const f32x4 b2v = *reinterpret_cast<const f32x4*>(b2 + (size_t)e * D_DIM + dout);
                atomicAdd(orow + dout + 0, g * (acc2[dn][tn][0] + b2v[0]));
                atomicAdd(orow + dout + 1, g * (acc2[dn][tn][1] + b2v[1]));
                atomicAdd(orow + dout + 2, g * (acc2[dn][tn][2] + b2v[2]));
                atomicAdd(orow + dout + 3, g * (acc2[dn][tn][3] + b2v[3]));
            }
        }
    }
}

extern "C" void kernel_launch(void* const* d_in, const int* in_sizes, int n_in,
                              void* d_out, int out_size, void* d_ws, size_t ws_size,
                              hipStream_t stream)
{
    const float* x  = (const float*)d_in[0];
    const float* Wr = (const float*)d_in[1];
    const float* br = (const float*)d_in[2];
    const float* W1 = (const float*)d_in[3];
    const float* b1 = (const float*)d_in[4];
    const float* W2 = (const float*)d_in[5];
    const float* b2 = (const float*)d_in[6];
    float* out = (float*)d_out;

    char* ws = (char*)d_ws;
    int*   g_cnt     = (int*)ws;                                    // 128 B (256 reserved)
    int*   list_tok  = (int*)(ws + 256);                            // 4 MB
    float* list_gate = (float*)(ws + 256 + (size_t)4194304);        // 4 MB
    unsigned short* xb  = (unsigned short*)(ws + 256 + (size_t)8388608);              // 8 MB
    unsigned short* W1t = (unsigned short*)(ws + 256 + (size_t)8388608 + 8388608);    // 4 MB
    unsigned short* W2t = (unsigned short*)(ws + 256 + (size_t)8388608 + 8388608 + 4194304); // 4 MB

    hipMemsetAsync(g_cnt, 0, E_EXP * sizeof(int), stream);
    hipMemsetAsync(out, 0, (size_t)out_size * sizeof(float), stream);

    moe_convert<<<dim3(4096), dim3(256), 0, stream>>>(x, W1, W2, xb, W1t, W2t);
    moe_router<<<dim3(T_TOK / 256), dim3(256), 0, stream>>>(x, Wr, br, g_cnt, list_tok, list_gate);
    moe_ffn<<<dim3(T_TOK / TILE, E_EXP), dim3(256), 0, stream>>>(xb, W1t, W2t, b1, b2, g_cnt,
                                                                 list_tok, list_gate, out);
}

// Round 10
// 292.376 us; speedup vs baseline: 3.6785x; 2.0473x over previous
//
#include <hip/hip_runtime.h>
#include <hip/hip_bf16.h>
#include <stdint.h>

#define T_TOK 32768
#define D_DIM 128
#define E_EXP 32
#define K_TOP 8
#define DFF_DIM 512
#define TILE 128          // tokens per ffn block
#define NCHUNK 8          // DFF chunks of 64

typedef __attribute__((ext_vector_type(8))) short  s16x8;
typedef __attribute__((ext_vector_type(4))) float  f32x4;

__device__ inline unsigned short f2bf(float f) {
    union { float f; unsigned u; } v; v.f = f;
    unsigned r = (v.u + 0x7fffu + ((v.u >> 16) & 1u)) >> 16;
    return (unsigned short)r;
}

// ---------------- convert: x -> bf16, W1/W2 -> fragment-linear bf16 ----------------
extern "C" __global__ __launch_bounds__(256)
void moe_convert(const float* __restrict__ x, const float* __restrict__ W1,
                 const float* __restrict__ W2, unsigned short* __restrict__ xb,
                 unsigned short* __restrict__ W1t, unsigned short* __restrict__ W2t)
{
    const int b = blockIdx.x, t = threadIdx.x;
    if (b < 2048) {
        const size_t i0 = ((size_t)b * 256 + t) * 8;
        const float4 a = *reinterpret_cast<const float4*>(x + i0);
        const float4 c = *reinterpret_cast<const float4*>(x + i0 + 4);
        s16x8 v;
        v[0]=(short)f2bf(a.x); v[1]=(short)f2bf(a.y); v[2]=(short)f2bf(a.z); v[3]=(short)f2bf(a.w);
        v[4]=(short)f2bf(c.x); v[5]=(short)f2bf(c.y); v[6]=(short)f2bf(c.z); v[7]=(short)f2bf(c.w);
        *reinterpret_cast<s16x8*>(xb + i0) = v;
    } else if (b < 3072) {
        const int fid = (b - 2048) * 256 + t;     // 0..262143
        const int l  = fid & 63;
        const int n  = (fid >> 6) & 3;
        const int s  = (fid >> 8) & 3;
        const int fc = (fid >> 10) & 7;
        const int e  = fid >> 13;
        const int f  = fc * 64 + n * 16 + (l & 15);
        const int d0 = s * 32 + (l >> 4) * 8;
        s16x8 v;
        #pragma unroll
        for (int j = 0; j < 8; ++j)
            v[j] = (short)f2bf(W1[((size_t)e * D_DIM + d0 + j) * DFF_DIM + f]);
        *reinterpret_cast<s16x8*>(W1t + (size_t)fid * 8) = v;
    } else {
        const int fid = (b - 3072) * 256 + t;
        const int l  = fid & 63;
        const int n  = (fid >> 6) & 7;
        const int sp = (fid >> 9) & 1;
        const int fc = (fid >> 10) & 7;
        const int e  = fid >> 13;
        const int dout = n * 16 + (l & 15);
        const int f0   = fc * 64 + sp * 32 + (l >> 4) * 8;
        s16x8 v;
        #pragma unroll
        for (int j = 0; j < 8; ++j)
            v[j] = (short)f2bf(W2[((size_t)e * DFF_DIM + f0 + j) * D_DIM + dout]);
        *reinterpret_cast<s16x8*>(W2t + (size_t)fid * 8) = v;
    }
}

// ---------------- Router: list entries now pack (token*8 + k) ----------------
extern "C" __global__ __launch_bounds__(256)
void moe_router(const float* __restrict__ x, const float* __restrict__ Wr,
                const float* __restrict__ br, int* __restrict__ g_cnt,
                int* __restrict__ list_tok, float* __restrict__ list_gate)
{
    __shared__ float Wrs[E_EXP * D_DIM];
    __shared__ float brs[E_EXP];
    __shared__ int cnt_s[E_EXP];
    __shared__ int base_s[E_EXP];
    const int tid = threadIdx.x;
    for (int i = tid; i < E_EXP * D_DIM; i += 256) Wrs[i] = Wr[i];
    if (tid < E_EXP) { brs[tid] = br[tid]; cnt_s[tid] = 0; }
    __syncthreads();

    const int t = blockIdx.x * 256 + tid;
    float logits[E_EXP];
    #pragma unroll
    for (int e = 0; e < E_EXP; ++e) logits[e] = brs[e];

    const float4* xr = reinterpret_cast<const float4*>(x + (size_t)t * D_DIM);
    for (int dc = 0; dc < D_DIM / 4; ++dc) {
        const float4 xv = xr[dc];
        #pragma unroll
        for (int e = 0; e < E_EXP; ++e) {
            const float4 wv = reinterpret_cast<const float4*>(Wrs + e * D_DIM)[dc];
            logits[e] = fmaf(xv.x, wv.x, fmaf(xv.y, wv.y, fmaf(xv.z, wv.z, fmaf(xv.w, wv.w, logits[e]))));
        }
    }

    float vals[K_TOP]; int ids[K_TOP];
    #pragma unroll
    for (int k = 0; k < K_TOP; ++k) {
        float m = -3e38f; int mi = 0;
        #pragma unroll
        for (int e = 0; e < E_EXP; ++e) if (logits[e] > m) { m = logits[e]; mi = e; }
        vals[k] = m; ids[k] = mi;
        #pragma unroll
        for (int e = 0; e < E_EXP; ++e) if (e == mi) logits[e] = -3e38f;
    }
    float s = 0.f, w[K_TOP];
    #pragma unroll
    for (int k = 0; k < K_TOP; ++k) { w[k] = expf(vals[k] - vals[0]); s += w[k]; }
    const float inv = 1.f / s;

    int pos[K_TOP];
    #pragma unroll
    for (int k = 0; k < K_TOP; ++k) pos[k] = atomicAdd(&cnt_s[ids[k]], 1);
    __syncthreads();
    if (tid < E_EXP) base_s[tid] = atomicAdd(&g_cnt[tid], cnt_s[tid]);
    __syncthreads();
    #pragma unroll
    for (int k = 0; k < K_TOP; ++k) {
        const int e = ids[k];
        const int p = base_s[e] + pos[k];
        list_tok[e * T_TOK + p]  = t * 8 + k;     // packed (token, k)
        list_gate[e * T_TOK + p] = w[k] * inv;
    }
}

// ---------------- MFMA expert FFN -> private slot writes (no atomics) ----------------
extern "C" __global__ __launch_bounds__(256, 2)
void moe_ffn(const unsigned short* __restrict__ xb,
             const unsigned short* __restrict__ W1t,
             const unsigned short* __restrict__ W2t,
             const float* __restrict__ b1, const float* __restrict__ b2,
             const int* __restrict__ g_cnt, const int* __restrict__ list_tok,
             const float* __restrict__ list_gate, float* __restrict__ slots)
{
    const int e = blockIdx.y;
    const int cnt = g_cnt[e];
    const int tile0 = blockIdx.x * TILE;
    if (tile0 >= cnt) return;

    __shared__ unsigned short Xs[TILE * D_DIM];   // 32 KB  fragment-linear
    __shared__ unsigned short Ws[64 * D_DIM];     // 16 KB  union: W1 / W2 chunk
    __shared__ unsigned short Hs[TILE * 64];      // 16 KB  [tok][f], 16B-slot XOR swizzled

    const int tid  = threadIdx.x;
    const int lane = tid & 63;
    const int w    = tid >> 6;
    const int lo   = lane & 15, hi = lane >> 4;

    // ---- gather X fragments (bf16) ----
    #pragma unroll
    for (int it = 0; it < 8; ++it) {
        const int fid = it * 256 + tid;
        const int l = fid & 63, s = (fid >> 6) & 3, m = fid >> 8;
        const int gt = tile0 + m * 16 + (l & 15);
        s16x8 v = {0,0,0,0,0,0,0,0};
        if (gt < cnt) {
            const int tok = list_tok[e * T_TOK + gt] >> 3;
            v = *reinterpret_cast<const s16x8*>(xb + (size_t)tok * D_DIM + s * 32 + (l >> 4) * 8);
        }
        *reinterpret_cast<s16x8*>(Xs + fid * 8) = v;
    }

    f32x4 acc2[4][4];
    #pragma unroll
    for (int i = 0; i < 4; ++i)
        #pragma unroll
        for (int j = 0; j < 4; ++j) acc2[i][j] = (f32x4){0.f, 0.f, 0.f, 0.f};

    const int wm = w & 1, wn = w >> 1;
    const int wt = w & 1, wd = w >> 1;

    for (int fc = 0; fc < NCHUNK; ++fc) {
        __syncthreads();
        {
            const unsigned short* src = W1t + (size_t)(e * 8 + fc) * 8192;
            #pragma unroll
            for (int it = 0; it < 4; ++it) {
                const int i = it * 256 + tid;
                *reinterpret_cast<s16x8*>(Ws + i * 8) =
                    *reinterpret_cast<const s16x8*>(src + i * 8);
            }
        }
        __syncthreads();

        // ---- GEMM1 ----
        f32x4 acc1[4][2];
        #pragma unroll
        for (int m = 0; m < 4; ++m) { acc1[m][0] = (f32x4){0,0,0,0}; acc1[m][1] = (f32x4){0,0,0,0}; }
        #pragma unroll
        for (int s = 0; s < 4; ++s) {
            const s16x8 a0 = *reinterpret_cast<const s16x8*>(Ws + ((s * 4 + wn * 2 + 0) * 64 + lane) * 8);
            const s16x8 a1 = *reinterpret_cast<const s16x8*>(Ws + ((s * 4 + wn * 2 + 1) * 64 + lane) * 8);
            #pragma unroll
            for (int m = 0; m < 4; ++m) {
                const s16x8 bx = *reinterpret_cast<const s16x8*>(Xs + (((wm * 4 + m) * 4 + s) * 64 + lane) * 8);
                acc1[m][0] = __builtin_amdgcn_mfma_f32_16x16x32_bf16(a0, bx, acc1[m][0], 0, 0, 0);
                acc1[m][1] = __builtin_amdgcn_mfma_f32_16x16x32_bf16(a1, bx, acc1[m][1], 0, 0, 0);
            }
        }

        // bias + relu + pack to Hs (swizzled)
        #pragma unroll
        for (int nn = 0; nn < 2; ++nn) {
            const f32x4 b1v = *reinterpret_cast<const f32x4*>(
                b1 + (size_t)e * DFF_DIM + fc * 64 + (wn * 2 + nn) * 16 + 4 * hi);
            #pragma unroll
            for (int m = 0; m < 4; ++m) {
                f32x4 v = acc1[m][nn];
                const float h0 = fmaxf(v[0] + b1v[0], 0.f);
                const float h1 = fmaxf(v[1] + b1v[1], 0.f);
                const float h2 = fmaxf(v[2] + b1v[2], 0.f);
                const float h3 = fmaxf(v[3] + b1v[3], 0.f);
                const unsigned w0 = (unsigned)f2bf(h0) | ((unsigned)f2bf(h1) << 16);
                const unsigned w1 = (unsigned)f2bf(h2) | ((unsigned)f2bf(h3) << 16);
                const int row  = (wm * 4 + m) * 16 + lo;
                const int slot = ((wn * 2 + nn) * 2 + (hi >> 1)) ^ (row & 7);
                char* p = reinterpret_cast<char*>(Hs) + row * 128 + slot * 16 + (hi & 1) * 8;
                *reinterpret_cast<uint2*>(p) = make_uint2(w0, w1);
            }
        }
        __syncthreads();

        {
            const unsigned short* src = W2t + (size_t)(e * 8 + fc) * 8192;
            #pragma unroll
            for (int it = 0; it < 4; ++it) {
                const int i = it * 256 + tid;
                *reinterpret_cast<s16x8*>(Ws + i * 8) =
                    *reinterpret_cast<const s16x8*>(src + i * 8);
            }
        }
        __syncthreads();

        // ---- GEMM2 ----
        #pragma unroll
        for (int sp = 0; sp < 2; ++sp) {
            s16x8 bh[4];
            #pragma unroll
            for (int tn = 0; tn < 4; ++tn) {
                const int row  = (wt * 4 + tn) * 16 + lo;
                const int slot = (sp * 4 + hi) ^ (row & 7);
                bh[tn] = *reinterpret_cast<const s16x8*>(
                    reinterpret_cast<char*>(Hs) + row * 128 + slot * 16);
            }
            #pragma unroll
            for (int dn = 0; dn < 4; ++dn) {
                const s16x8 aw = *reinterpret_cast<const s16x8*>(
                    Ws + ((sp * 8 + wd * 4 + dn) * 64 + lane) * 8);
                acc2[dn][0] = __builtin_amdgcn_mfma_f32_16x16x32_bf16(aw, bh[0], acc2[dn][0], 0, 0, 0);
                acc2[dn][1] = __builtin_amdgcn_mfma_f32_16x16x32_bf16(aw, bh[1], acc2[dn][1], 0, 0, 0);
                acc2[dn][2] = __builtin_amdgcn_mfma_f32_16x16x32_bf16(aw, bh[2], acc2[dn][2], 0, 0, 0);
                acc2[dn][3] = __builtin_amdgcn_mfma_f32_16x16x32_bf16(aw, bh[3], acc2[dn][3], 0, 0, 0);
            }
        }
    }

    // ---- epilogue: slots[t*8+k][dout] = gate * (acc2 + b2), plain stores ----
    #pragma unroll
    for (int tn = 0; tn < 4; ++tn) {
        const int gt = tile0 + (wt * 4 + tn) * 16 + lo;
        if (gt < cnt) {
            const int   entry = list_tok[e * T_TOK + gt];       // t*8+k
            const float g     = list_gate[e * T_TOK + gt];
            float* srow = slots + (size_t)entry * D_DIM;
            #pragma unroll
            for (int dn = 0; dn < 4; ++dn) {
                const int dout = (wd * 4 + dn) * 16 + 4 * hi;
                const f32x4 b2v = *reinterpret_cast<const f32x4*>(b2 + (size_t)e * D_DIM + dout);
                f32x4 vv;
                vv[0] = g * (acc2[dn][tn][0] + b2v[0]);
                vv[1] = g * (acc2[dn][tn][1] + b2v[1]);
                vv[2] = g * (acc2[dn][tn][2] + b2v[2]);
                vv[3] = g * (acc2[dn][tn][3] + b2v[3]);
                *reinterpret_cast<f32x4*>(srow + dout) = vv;
            }
        }
    }
}

// ---------------- combine: out[t][d] = sum_k slots[t*8+k][d] ----------------
extern "C" __global__ __launch_bounds__(256)
void moe_combine(const float* __restrict__ slots, float* __restrict__ out)
{
    const int tid = threadIdx.x;
    const int t  = blockIdx.x * 8 + (tid >> 5);
    const int d4 = (tid & 31) * 4;
    const float* base = slots + ((size_t)t * 8) * D_DIM + d4;
    f32x4 s = *reinterpret_cast<const f32x4*>(base);
    #pragma unroll
    for (int k = 1; k < K_TOP; ++k) {
        const f32x4 v = *reinterpret_cast<const f32x4*>(base + (size_t)k * D_DIM);
        s[0] += v[0]; s[1] += v[1]; s[2] += v[2]; s[3] += v[3];
    }
    *reinterpret_cast<f32x4*>(out + (size_t)t * D_DIM + d4) = s;
}

extern "C" void kernel_launch(void* const* d_in, const int* in_sizes, int n_in,
                              void* d_out, int out_size, void* d_ws, size_t ws_size,
                              hipStream_t stream)
{
    const float* x  = (const float*)d_in[0];
    const float* Wr = (const float*)d_in[1];
    const float* br = (const float*)d_in[2];
    const float* W1 = (const float*)d_in[3];
    const float* b1 = (const float*)d_in[4];
    const float* W2 = (const float*)d_in[5];
    const float* b2 = (const float*)d_in[6];
    float* out = (float*)d_out;

    char* ws = (char*)d_ws;
    float* slots = (float*)ws;                                  // 134,217,728 B
    size_t off = (size_t)T_TOK * K_TOP * D_DIM * 4;
    int*   g_cnt     = (int*)(ws + off);                        // 256 B reserved
    int*   list_tok  = (int*)(ws + off + 256);                  // 4 MB
    float* list_gate = (float*)(ws + off + 256 + 4194304);      // 4 MB
    unsigned short* xb  = (unsigned short*)(ws + off + 256 + 8388608);               // 8 MB
    unsigned short* W1t = (unsigned short*)(ws + off + 256 + 8388608 + 8388608);     // 4 MB
    unsigned short* W2t = (unsigned short*)(ws + off + 256 + 8388608 + 8388608 + 4194304); // 4 MB

    hipMemsetAsync(g_cnt, 0, E_EXP * sizeof(int), stream);

    moe_convert<<<dim3(4096), dim3(256), 0, stream>>>(x, W1, W2, xb, W1t, W2t);
    moe_router<<<dim3(T_TOK / 256), dim3(256), 0, stream>>>(x, Wr, br, g_cnt, list_tok, list_gate);
    moe_ffn<<<dim3(T_TOK / TILE, E_EXP), dim3(256), 0, stream>>>(xb, W1t, W2t, b1, b2, g_cnt,
                                                                 list_tok, list_gate, slots);
    moe_combine<<<dim3(T_TOK / 8), dim3(256), 0, stream>>>(slots, out);
}

// Round 12
// 271.077 us; speedup vs baseline: 3.9675x; 1.0786x over previous
//
#include <hip/hip_runtime.h>
#include <hip/hip_bf16.h>
#include <stdint.h>

#define T_TOK 32768
#define D_DIM 128
#define E_EXP 32
#define K_TOP 8
#define DFF_DIM 512
#define TILE 128          // tokens per ffn block
#define NCHUNK 8          // DFF chunks of 64

typedef __attribute__((ext_vector_type(8)))  short s16x8;
typedef __attribute__((ext_vector_type(4)))  float f32x4;
typedef __attribute__((ext_vector_type(16))) float f32x16;

__device__ inline unsigned short f2bf(float f) {
    union { float f; unsigned u; } v; v.f = f;
    unsigned r = (v.u + 0x7fffu + ((v.u >> 16) & 1u)) >> 16;
    return (unsigned short)r;
}

__device__ __forceinline__ void gld16(const unsigned short* g, unsigned short* l) {
    __builtin_amdgcn_global_load_lds(
        (const __attribute__((address_space(1))) void*)g,
        (__attribute__((address_space(3))) void*)l, 16, 0, 0);
}

// ---------------- convert: x -> bf16, W1/W2 -> 32x32x16 fragment-linear bf16 ----------------
// W1t frag: (((e*8+fc)*2 + n)*8 + ks)*64 + l ; elem j = W1[e][d=ks*16+(l>>5)*8+j][f=fc*64+n*32+(l&31)]
// W2t frag: (((e*8+fc)*4 + dt)*4 + ks2)*64 + l; elem j = W2[e][f=fc*64+ks2*16+(l>>5)*8+j][dout=dt*32+(l&31)]
extern "C" __global__ __launch_bounds__(256)
void moe_convert(const float* __restrict__ x, const float* __restrict__ W1,
                 const float* __restrict__ W2, unsigned short* __restrict__ xb,
                 unsigned short* __restrict__ W1t, unsigned short* __restrict__ W2t)
{
    const int b = blockIdx.x, t = threadIdx.x;
    if (b < 2048) {
        const size_t i0 = ((size_t)b * 256 + t) * 8;
        const float4 a = *reinterpret_cast<const float4*>(x + i0);
        const float4 c = *reinterpret_cast<const float4*>(x + i0 + 4);
        s16x8 v;
        v[0]=(short)f2bf(a.x); v[1]=(short)f2bf(a.y); v[2]=(short)f2bf(a.z); v[3]=(short)f2bf(a.w);
        v[4]=(short)f2bf(c.x); v[5]=(short)f2bf(c.y); v[6]=(short)f2bf(c.z); v[7]=(short)f2bf(c.w);
        *reinterpret_cast<s16x8*>(xb + i0) = v;
    } else if (b < 3072) {
        const int t2 = (b - 2048) * 256 + t;     // 0..262143
        const int l  = t2 & 63;
        const int ks = (t2 >> 6) & 7;
        const int n  = (t2 >> 9) & 1;
        const int fc = (t2 >> 10) & 7;
        const int e  = t2 >> 13;
        const int f  = fc * 64 + n * 32 + (l & 31);
        const int d0 = ks * 16 + (l >> 5) * 8;
        s16x8 v;
        #pragma unroll
        for (int j = 0; j < 8; ++j)
            v[j] = (short)f2bf(W1[((size_t)e * D_DIM + d0 + j) * DFF_DIM + f]);
        *reinterpret_cast<s16x8*>(W1t + (size_t)t2 * 8) = v;
    } else {
        const int t2 = (b - 3072) * 256 + t;
        const int l   = t2 & 63;
        const int ks2 = (t2 >> 6) & 3;
        const int dt  = (t2 >> 8) & 3;
        const int fc  = (t2 >> 10) & 7;
        const int e   = t2 >> 13;
        const int dout = dt * 32 + (l & 31);
        const int f0   = fc * 64 + ks2 * 16 + (l >> 5) * 8;
        s16x8 v;
        #pragma unroll
        for (int j = 0; j < 8; ++j)
            v[j] = (short)f2bf(W2[((size_t)e * DFF_DIM + f0 + j) * D_DIM + dout]);
        *reinterpret_cast<s16x8*>(W2t + (size_t)t2 * 8) = v;
    }
}

// ---------------- Router (unchanged; packs t*8+k) ----------------
extern "C" __global__ __launch_bounds__(256)
void moe_router(const float* __restrict__ x, const float* __restrict__ Wr,
                const float* __restrict__ br, int* __restrict__ g_cnt,
                int* __restrict__ list_tok, float* __restrict__ list_gate)
{
    __shared__ float Wrs[E_EXP * D_DIM];
    __shared__ float brs[E_EXP];
    __shared__ int cnt_s[E_EXP];
    __shared__ int base_s[E_EXP];
    const int tid = threadIdx.x;
    for (int i = tid; i < E_EXP * D_DIM; i += 256) Wrs[i] = Wr[i];
    if (tid < E_EXP) { brs[tid] = br[tid]; cnt_s[tid] = 0; }
    __syncthreads();

    const int t = blockIdx.x * 256 + tid;
    float logits[E_EXP];
    #pragma unroll
    for (int e = 0; e < E_EXP; ++e) logits[e] = brs[e];

    const float4* xr = reinterpret_cast<const float4*>(x + (size_t)t * D_DIM);
    for (int dc = 0; dc < D_DIM / 4; ++dc) {
        const float4 xv = xr[dc];
        #pragma unroll
        for (int e = 0; e < E_EXP; ++e) {
            const float4 wv = reinterpret_cast<const float4*>(Wrs + e * D_DIM)[dc];
            logits[e] = fmaf(xv.x, wv.x, fmaf(xv.y, wv.y, fmaf(xv.z, wv.z, fmaf(xv.w, wv.w, logits[e]))));
        }
    }

    float vals[K_TOP]; int ids[K_TOP];
    #pragma unroll
    for (int k = 0; k < K_TOP; ++k) {
        float m = -3e38f; int mi = 0;
        #pragma unroll
        for (int e = 0; e < E_EXP; ++e) if (logits[e] > m) { m = logits[e]; mi = e; }
        vals[k] = m; ids[k] = mi;
        #pragma unroll
        for (int e = 0; e < E_EXP; ++e) if (e == mi) logits[e] = -3e38f;
    }
    float s = 0.f, w[K_TOP];
    #pragma unroll
    for (int k = 0; k < K_TOP; ++k) { w[k] = expf(vals[k] - vals[0]); s += w[k]; }
    const float inv = 1.f / s;

    int pos[K_TOP];
    #pragma unroll
    for (int k = 0; k < K_TOP; ++k) pos[k] = atomicAdd(&cnt_s[ids[k]], 1);
    __syncthreads();
    if (tid < E_EXP) base_s[tid] = atomicAdd(&g_cnt[tid], cnt_s[tid]);
    __syncthreads();
    #pragma unroll
    for (int k = 0; k < K_TOP; ++k) {
        const int e = ids[k];
        const int p = base_s[e] + pos[k];
        list_tok[e * T_TOK + p]  = t * 8 + k;
        list_gate[e * T_TOK + p] = w[k] * inv;
    }
}

// ---------------- MFMA expert FFN: 8 waves, 32x32x16, X-in-regs, async W pipeline ----------------
extern "C" __global__ __launch_bounds__(512, 4)
void moe_ffn(const unsigned short* __restrict__ xb,
             const unsigned short* __restrict__ W1t,
             const unsigned short* __restrict__ W2t,
             const float* __restrict__ b1, const float* __restrict__ b2,
             const int* __restrict__ g_cnt, const int* __restrict__ list_tok,
             const float* __restrict__ list_gate, float* __restrict__ slots)
{
    // XCD-grouped decode: expert pinned to one XCD slot for W L2 locality
    const int lin   = blockIdx.x;
    const int e     = (lin & 7) * 4 + ((lin >> 3) & 3);
    const int tile0 = (lin >> 5) * TILE;
    const int cnt   = g_cnt[e];
    if (tile0 >= cnt) return;

    __shared__ unsigned short WsA[8192];  // W1 chunk, 16 KB
    __shared__ unsigned short WsB[8192];  // W2 chunk, 16 KB
    __shared__ unsigned short Hs[8192];   // H [tok128][f64], 16B-slot XOR swizzled, 16 KB

    const int tid  = threadIdx.x;
    const int w    = tid >> 6;
    const int lane = tid & 63;
    const int h    = lane >> 5;           // k-half
    const int l31  = lane & 31;
    const int wf   = w & 1;               // f-tile (GEMM1) / dout-half (GEMM2)
    const int wtok = w >> 1;              // token tile (both GEMMs)

    // ---- tokens & gates for this wave's 32-token strip ----
    const int gt    = tile0 + wtok * 32 + l31;
    const bool valid = gt < cnt;
    int entry = 0; float gate = 0.f;
    if (valid) { entry = list_tok[e * T_TOK + gt]; gate = list_gate[e * T_TOK + gt]; }
    const int tokid = entry >> 3;

    // ---- issue W1(0), W2(0) staging ----
    const unsigned short* w1src = W1t + (size_t)e * 8 * 8192;
    const unsigned short* w2src = W2t + (size_t)e * 8 * 8192;
    {
        const int o0 = (0 * 8 + w) * 64, o1 = (1 * 8 + w) * 64;
        gld16(w1src + (size_t)(o0 + lane) * 8, WsA + o0 * 8);
        gld16(w1src + (size_t)(o1 + lane) * 8, WsA + o1 * 8);
        gld16(w2src + (size_t)(o0 + lane) * 8, WsB + o0 * 8);
        gld16(w2src + (size_t)(o1 + lane) * 8, WsB + o1 * 8);
    }

    // ---- gather X fragments into registers (reused by all 8 chunks) ----
    s16x8 xf[8];
    #pragma unroll
    for (int ks = 0; ks < 8; ++ks) {
        s16x8 v = {0,0,0,0,0,0,0,0};
        if (valid)
            v = *reinterpret_cast<const s16x8*>(xb + (size_t)tokid * D_DIM + ks * 16 + h * 8);
        xf[ks] = v;
    }

    f32x16 acc2a = {0,0,0,0,0,0,0,0,0,0,0,0,0,0,0,0};
    f32x16 acc2b = {0,0,0,0,0,0,0,0,0,0,0,0,0,0,0,0};
    const int hrow  = wtok * 32 + l31;          // Hs row (token-in-tile)
    char* hbase = reinterpret_cast<char*>(Hs) + hrow * 128;
    const int hx = hrow & 7;

    for (int fc = 0; fc < NCHUNK; ++fc) {
        __syncthreads();   // bar1: W1(fc) (+W2(0)) landed everywhere; WsB free
        if (fc > 0) {      // W2(fc) lands during GEMM1, drained at bar2
            const unsigned short* src = w2src + (size_t)fc * 8192;
            const int o0 = (0 * 8 + w) * 64, o1 = (1 * 8 + w) * 64;
            gld16(src + (size_t)(o0 + lane) * 8, WsB + o0 * 8);
            gld16(src + (size_t)(o1 + lane) * 8, WsB + o1 * 8);
        }

        // ---- GEMM1: acc1[f32][tok32] over d=128 ----
        f32x16 acc1 = {0,0,0,0,0,0,0,0,0,0,0,0,0,0,0,0};
        #pragma unroll
        for (int ks = 0; ks < 8; ++ks) {
            const s16x8 a = *reinterpret_cast<const s16x8*>(WsA + ((wf * 8 + ks) * 64 + lane) * 8);
            acc1 = __builtin_amdgcn_mfma_f32_32x32x16_bf16(a, xf[ks], acc1, 0, 0, 0);
        }

        // ---- bias + relu + pack -> Hs (swizzled) ----
        #pragma unroll
        for (int rq = 0; rq < 4; ++rq) {
            const f32x4 b1v = *reinterpret_cast<const f32x4*>(
                b1 + (size_t)e * DFF_DIM + fc * 64 + wf * 32 + rq * 8 + h * 4);
            const float v0 = fmaxf(acc1[4*rq+0] + b1v[0], 0.f);
            const float v1 = fmaxf(acc1[4*rq+1] + b1v[1], 0.f);
            const float v2 = fmaxf(acc1[4*rq+2] + b1v[2], 0.f);
            const float v3 = fmaxf(acc1[4*rq+3] + b1v[3], 0.f);
            const unsigned p0 = (unsigned)f2bf(v0) | ((unsigned)f2bf(v1) << 16);
            const unsigned p1 = (unsigned)f2bf(v2) | ((unsigned)f2bf(v3) << 16);
            *reinterpret_cast<uint2*>(hbase + (((wf * 4 + rq) ^ hx) * 16) + h * 8) =
                make_uint2(p0, p1);
        }

        __syncthreads();   // bar2: Hs visible + W2(fc) landed everywhere + WsA free
        if (fc < NCHUNK - 1) {   // W1(fc+1) lands during GEMM2, drained at next bar1
            const unsigned short* src = w1src + (size_t)(fc + 1) * 8192;
            const int o0 = (0 * 8 + w) * 64, o1 = (1 * 8 + w) * 64;
            gld16(src + (size_t)(o0 + lane) * 8, WsA + o0 * 8);
            gld16(src + (size_t)(o1 + lane) * 8, WsA + o1 * 8);
        }

        // ---- GEMM2: acc2 [dout 2x32][tok32] over f=64, accumulated across chunks ----
        #pragma unroll
        for (int ks2 = 0; ks2 < 4; ++ks2) {
            const s16x8 bh = *reinterpret_cast<const s16x8*>(
                hbase + (((ks2 * 2 + h) ^ hx) * 16));
            const s16x8 aw0 = *reinterpret_cast<const s16x8*>(
                WsB + (((wf * 2 + 0) * 4 + ks2) * 64 + lane) * 8);
            const s16x8 aw1 = *reinterpret_cast<const s16x8*>(
                WsB + (((wf * 2 + 1) * 4 + ks2) * 64 + lane) * 8);
            acc2a = __builtin_amdgcn_mfma_f32_32x32x16_bf16(aw0, bh, acc2a, 0, 0, 0);
            acc2b = __builtin_amdgcn_mfma_f32_32x32x16_bf16(aw1, bh, acc2b, 0, 0, 0);
        }
    }

    // ---- epilogue: slots[entry][dout] = gate * (acc2 + b2) ----
    if (valid) {
        float* srow = slots + (size_t)entry * D_DIM;
        #pragma unroll
        for (int q = 0; q < 2; ++q) {
            #pragma unroll
            for (int rq = 0; rq < 4; ++rq) {
                const int dout = (wf * 2 + q) * 32 + rq * 8 + h * 4;
                const f32x4 b2v = *reinterpret_cast<const f32x4*>(b2 + (size_t)e * D_DIM + dout);
                f32x4 vv;
                if (q == 0) {
                    vv[0] = gate * (acc2a[4*rq+0] + b2v[0]);
                    vv[1] = gate * (acc2a[4*rq+1] + b2v[1]);
                    vv[2] = gate * (acc2a[4*rq+2] + b2v[2]);
                    vv[3] = gate * (acc2a[4*rq+3] + b2v[3]);
                } else {
                    vv[0] = gate * (acc2b[4*rq+0] + b2v[0]);
                    vv[1] = gate * (acc2b[4*rq+1] + b2v[1]);
                    vv[2] = gate * (acc2b[4*rq+2] + b2v[2]);
                    vv[3] = gate * (acc2b[4*rq+3] + b2v[3]);
                }
                *reinterpret_cast<f32x4*>(srow + dout) = vv;
            }
        }
    }
}

// ---------------- combine: out[t][d] = sum_k slots[t*8+k][d] ----------------
extern "C" __global__ __launch_bounds__(256)
void moe_combine(const float* __restrict__ slots, float* __restrict__ out)
{
    const int tid = threadIdx.x;
    const int t  = blockIdx.x * 8 + (tid >> 5);
    const int d4 = (tid & 31) * 4;
    const float* base = slots + ((size_t)t * 8) * D_DIM + d4;
    f32x4 s = *reinterpret_cast<const f32x4*>(base);
    #pragma unroll
    for (int k = 1; k < K_TOP; ++k) {
        const f32x4 v = *reinterpret_cast<const f32x4*>(base + (size_t)k * D_DIM);
        s[0] += v[0]; s[1] += v[1]; s[2] += v[2]; s[3] += v[3];
    }
    *reinterpret_cast<f32x4*>(out + (size_t)t * D_DIM + d4) = s;
}

extern "C" void kernel_launch(void* const* d_in, const int* in_sizes, int n_in,
                              void* d_out, int out_size, void* d_ws, size_t ws_size,
                              hipStream_t stream)
{
    const float* x  = (const float*)d_in[0];
    const float* Wr = (const float*)d_in[1];
    const float* br = (const float*)d_in[2];
    const float* W1 = (const float*)d_in[3];
    const float* b1 = (const float*)d_in[4];
    const float* W2 = (const float*)d_in[5];
    const float* b2 = (const float*)d_in[6];
    float* out = (float*)d_out;

    char* ws = (char*)d_ws;
    float* slots = (float*)ws;                                  // 134,217,728 B
    size_t off = (size_t)T_TOK * K_TOP * D_DIM * 4;
    int*   g_cnt     = (int*)(ws + off);                        // 256 B reserved
    int*   list_tok  = (int*)(ws + off + 256);                  // 4 MB
    float* list_gate = (float*)(ws + off + 256 + 4194304);      // 4 MB
    unsigned short* xb  = (unsigned short*)(ws + off + 256 + 8388608);               // 8 MB
    unsigned short* W1t = (unsigned short*)(ws + off + 256 + 8388608 + 8388608);     // 4 MB
    unsigned short* W2t = (unsigned short*)(ws + off + 256 + 8388608 + 8388608 + 4194304); // 4 MB

    hipMemsetAsync(g_cnt, 0, E_EXP * sizeof(int), stream);

    moe_convert<<<dim3(4096), dim3(256), 0, stream>>>(x, W1, W2, xb, W1t, W2t);
    moe_router<<<dim3(T_TOK / 256), dim3(256), 0, stream>>>(x, Wr, br, g_cnt, list_tok, list_gate);
    moe_ffn<<<dim3((T_TOK / TILE) * E_EXP), dim3(512), 0, stream>>>(xb, W1t, W2t, b1, b2, g_cnt,
                                                                    list_tok, list_gate, slots);
    moe_combine<<<dim3(T_TOK / 8), dim3(256), 0, stream>>>(slots, out);
}